// Round 1
// baseline (342.186 us; speedup 1.0000x reference)
//
#include <hip/hip_runtime.h>
#include <math.h>

#define XDIM 47764
#define HDIM 128
#define LDIM 8
#define VTDIM 3620
#define WDIM 32
#define RDIM 8
#define NDIM 512
#define RW 256            // W*R
#define DDIM 48276        // X + RW + 2H
#define FIXED 48148       // X + RW + H   (rows of si independent of h_prev_layer)
#define ETDIM 395
#define EPSV 1e-8f

#define CHUNK 768
#define NCHUNK 63         // ceil(48148/768)

// ws layout (float offsets)
#define OFF_PARTIAL 0          // 32*63*128 = 258048
#define OFF_FIXED   258048     // 32*128    = 4096
#define OFF_WREC    262144     // 32*128*128= 524288
#define OFF_FLAT    786432     // 1024
#define OFF_ERAW    787456     // 512 (memset to 0 each launch)
#define OFF_WW      787968     // 512
#define OFF_MEMNEW  788480     // 16384
#define OFF_CR      804864     // 4096
#define OFF_RM      808960     // 32
#define OFF_FW      808992     // 4096
#define OFF_BW      813088     // 4096
#define OFF_RV      817184     // 256

__device__ inline float sigm(float x) { return 1.f / (1.f + expf(-x)); }
__device__ inline float log_sigmoid(float x) {
    return (x >= 0.f) ? -log1pf(expf(-x)) : (x - log1pf(expf(x)));
}

// ---------------- K1: partial gate pre-activations over fixed rows ----------
__global__ __launch_bounds__(256) void k1_partial(
    const float* __restrict__ x_in, const float* __restrict__ lrv,
    const float* __restrict__ hprev,
    const float* __restrict__ Wi, const float* __restrict__ Wf,
    const float* __restrict__ Wo, const float* __restrict__ Ws,
    float* __restrict__ ws)
{
    const int bid   = blockIdx.x;
    const int combo = bid / NCHUNK;        // 0..31 : g*8 + l
    const int chunk = bid % NCHUNK;
    const int g = combo >> 3, l = combo & 7;
    const float* __restrict__ Wg = (g == 0) ? Wi : (g == 1) ? Wf : (g == 2) ? Wo : Ws;
    const int t  = threadIdx.x;
    const int d0 = chunk * CHUNK;

    __shared__ float s_lds[CHUNK];
    for (int i = t; i < CHUNK; i += 256) {
        int d = d0 + i;
        float v = 0.f;
        if (d < XDIM)            v = x_in[d];
        else if (d < XDIM + RW)  v = lrv[d - XDIM];
        else if (d < FIXED)      v = hprev[l * HDIM + (d - XDIM - RW)];
        s_lds[i] = v;
    }
    __syncthreads();

    const int h4 = t & 31;    // float4 column
    const int p  = t >> 5;    // row slice 0..7
    float4 acc = make_float4(0.f, 0.f, 0.f, 0.f);
    const size_t lbase = (size_t)l * DDIM * HDIM + (size_t)(h4 << 2);
    for (int rr = p; rr < CHUNK; rr += 8) {
        int d = d0 + rr;
        if (d >= FIXED) break;
        float s = s_lds[rr];
        const float4 w = *reinterpret_cast<const float4*>(Wg + lbase + (size_t)d * HDIM);
        acc.x += s * w.x; acc.y += s * w.y; acc.z += s * w.z; acc.w += s * w.w;
    }

    __shared__ float4 red[8][32];
    red[p][h4] = acc;
    __syncthreads();
    if (t < 32) {
        float4 sum = red[0][t];
        #pragma unroll
        for (int q = 1; q < 8; ++q) {
            float4 v = red[q][t];
            sum.x += v.x; sum.y += v.y; sum.z += v.z; sum.w += v.w;
        }
        *reinterpret_cast<float4*>(ws + OFF_PARTIAL +
            ((size_t)(combo * NCHUNK + chunk)) * HDIM + (t << 2)) = sum;
    }
}

// ------------- K2: reduce partials (+bias), compact recurrent weights ------
__global__ __launch_bounds__(256) void k2_reduce_compact(
    const float* __restrict__ Wi, const float* __restrict__ Wf,
    const float* __restrict__ Wo, const float* __restrict__ Ws,
    const float* __restrict__ bi, const float* __restrict__ bf,
    const float* __restrict__ bo, const float* __restrict__ bs,
    float* __restrict__ ws)
{
    const int blk = blockIdx.x, t = threadIdx.x;
    if (blk < 32) {
        if (t < 128) {
            int g = blk >> 3, l = blk & 7;
            const float* bg = (g == 0) ? bi : (g == 1) ? bf : (g == 2) ? bo : bs;
            float acc = bg[l * HDIM + t];
            const float* P = ws + OFF_PARTIAL + (size_t)blk * NCHUNK * HDIM;
            for (int c = 0; c < NCHUNK; ++c) acc += P[c * HDIM + t];
            ws[OFF_FIXED + blk * HDIM + t] = acc;
        }
    } else {
        // copy W*[l][FIXED + j][h] -> wrec[combo][j][h], float4 per thread
        int idx4  = (blk - 32) * 256 + t;        // 0..131071
        int flat  = idx4 << 2;                   // float idx 0..524284
        int combo = flat >> 14;
        int rem   = flat & 16383;
        int j = rem >> 7, h = rem & 127;
        int g = combo >> 3, l = combo & 7;
        const float* Wg = (g == 0) ? Wi : (g == 1) ? Wf : (g == 2) ? Wo : Ws;
        float4 v = *reinterpret_cast<const float4*>(
            Wg + ((size_t)l * DDIM + FIXED + j) * HDIM + h);
        *reinterpret_cast<float4*>(ws + OFF_WREC + flat) = v;
    }
}

// ---------------- K3: sequential layer chain (1 block) ---------------------
__global__ __launch_bounds__(512) void k3_recurrent(
    const float* __restrict__ old_states, float* __restrict__ ws)
{
    __shared__ float hp[128];
    __shared__ float gl[4][128];
    const int t = threadIdx.x;
    const int g = t >> 7, h = t & 127;
    if (t < 128) hp[t] = 0.f;
    __syncthreads();
    for (int l = 0; l < LDIM; ++l) {
        float acc = ws[OFF_FIXED + (g * 8 + l) * HDIM + h];
        const float* wr = ws + OFF_WREC + (size_t)(g * 8 + l) * 128 * 128 + h;
        #pragma unroll 16
        for (int j = 0; j < 128; ++j) acc += hp[j] * wr[j * 128];
        gl[g][h] = acc;
        __syncthreads();
        if (t < 128) {
            float ig = sigm(gl[0][t]);
            float fg = sigm(gl[1][t]);
            float og = sigm(gl[2][t]);
            float ss = tanhf(gl[3][t]);
            float st = fg * old_states[l * HDIM + t] + ig * ss;
            float hn = og * tanhf(st);
            hp[t] = hn;
            ws[OFF_FLAT + l * HDIM + t] = hn;
        }
        __syncthreads();
    }
}

// ---------------- K45: flat@W_y -> d_out, flat@W_E -> E_raw ----------------
__global__ __launch_bounds__(256) void k45_out_E(
    const float* __restrict__ Wy, const float* __restrict__ We,
    float* __restrict__ dout, float* __restrict__ ws)
{
    const int blk = blockIdx.x, t = threadIdx.x;
    __shared__ float fl[128];
    if (blk < 120) {
        int vt = blk % 15, kc = blk / 15;
        if (t < 128) fl[t] = ws[OFF_FLAT + kc * 128 + t];
        __syncthreads();
        int v = vt * 256 + t;
        if (v < VTDIM) {
            float acc = 0.f;
            const float* Wp = Wy + (size_t)kc * 128 * VTDIM + v;
            #pragma unroll 8
            for (int k = 0; k < 128; ++k) acc += fl[k] * Wp[(size_t)k * VTDIM];
            atomicAdd(&dout[v], acc);
        }
    } else {
        int kc = blk - 120;
        if (t < 128) fl[t] = ws[OFF_FLAT + kc * 128 + t];
        __syncthreads();
        if (t < ETDIM) {
            float acc = 0.f;
            const float* Wp = We + (size_t)kc * 128 * ETDIM + t;
            #pragma unroll 8
            for (int k = 0; k < 128; ++k) acc += fl[k] * Wp[k * ETDIM];
            atomicAdd(&ws[OFF_ERAW + t], acc);
        }
    }
}

// ---------------- K6: E unpack + usage/sort/alloc + write/memory/cr --------
__global__ __launch_bounds__(512) void k6_small(
    const float* __restrict__ memory, const float* __restrict__ lrw,
    const float* __restrict__ lu, const float* __restrict__ lww,
    float* __restrict__ ws)
{
    const int t = threadIdx.x;
    __shared__ float Es[400];
    __shared__ float rk[256], rs_s[8], wk[32], er[32], wv[32], fgs[8], rm[24], scal[4];
    __shared__ float u_s[512];
    __shared__ int   idx_s[512];
    __shared__ float cp[512], alloc_s[512], red[512], srk[8];

    if (t < ETDIM) Es[t] = ws[OFF_ERAW + t];
    __syncthreads();

    if (t < 256)                 rk[t] = Es[t];
    if (t >= 256 && t < 264)     rs_s[t - 256] = 1.f - log_sigmoid(Es[t]);
    if (t >= 264 && t < 296)     wk[t - 264] = Es[t];
    if (t == 296)                scal[0] = 1.f - log_sigmoid(Es[296]);   // write_strength
    if (t >= 297 && t < 329)     er[t - 297] = sigm(Es[t]);
    if (t >= 329 && t < 361)     wv[t - 329] = Es[t];
    if (t >= 361 && t < 369)     fgs[t - 361] = sigm(Es[t]);
    if (t == 369)                scal[1] = sigm(Es[369]);                // alloc_gate
    if (t == 370)                scal[2] = sigm(Es[370]);                // write_gate
    if (t >= 384 && t < 392) {                                          // read_modes
        int r = t - 384;
        float a = Es[371 + 3*r], b = Es[372 + 3*r], c = Es[373 + 3*r];
        float mx = fmaxf(a, fmaxf(b, c));
        float ea = expf(a - mx), eb = expf(b - mx), ec = expf(c - mx);
        float s = ea + eb + ec;
        rm[3*r] = ea / s; rm[3*r + 1] = eb / s; rm[3*r + 2] = ec / s;
    }
    __syncthreads();

    // psi / usage
    {
        float psi = 1.f;
        #pragma unroll
        for (int r = 0; r < 8; ++r) psi *= 1.f - fgs[r] * lrw[t * 8 + r];
        float a = lu[t], b = lww[t];
        u_s[t] = (a + b - a * b) * psi;
        idx_s[t] = t;
    }
    __syncthreads();

    // stable ascending bitonic sort on (u, idx)
    for (int k = 2; k <= 512; k <<= 1) {
        for (int j = k >> 1; j > 0; j >>= 1) {
            int ixj = t ^ j;
            if (ixj > t) {
                float a = u_s[t], b = u_s[ixj];
                int ia = idx_s[t], ib = idx_s[ixj];
                bool gt = (a > b) || (a == b && ia > ib);
                bool up = ((t & k) == 0);
                if (gt == up) {
                    u_s[t] = b; u_s[ixj] = a;
                    idx_s[t] = ib; idx_s[ixj] = ia;
                }
            }
            __syncthreads();
        }
    }

    // inclusive cumprod of sorted usage
    cp[t] = u_s[t];
    __syncthreads();
    for (int off = 1; off < 512; off <<= 1) {
        float v = (t >= off) ? cp[t - off] : 1.f;
        __syncthreads();
        cp[t] *= v;
        __syncthreads();
    }
    float excl = (t == 0) ? 1.f : cp[t - 1];
    alloc_s[idx_s[t]] = (1.f - u_s[t]) * excl;     // scatter = inverse permutation

    if (t == 0) {
        float s = 0.f;
        #pragma unroll
        for (int w = 0; w < 32; ++w) s += wk[w] * wk[w];
        scal[3] = 1.f / fmaxf(sqrtf(s), EPSV);
    }
    __syncthreads();

    // content write weighting
    float mrow[32];
    float dotv = 0.f, nn = 0.f;
    #pragma unroll
    for (int w = 0; w < 32; ++w) {
        float m = memory[t * 32 + w];
        mrow[w] = m; dotv += m * wk[w]; nn += m * m;
    }
    float score = scal[0] * scal[3] * dotv / fmaxf(sqrtf(nn), EPSV);
    red[t] = score; __syncthreads();
    for (int s = 256; s > 0; s >>= 1) { if (t < s) red[t] = fmaxf(red[t], red[t + s]); __syncthreads(); }
    float mx = red[0]; __syncthreads();
    float e = expf(score - mx);
    red[t] = e; __syncthreads();
    for (int s = 256; s > 0; s >>= 1) { if (t < s) red[t] += red[t + s]; __syncthreads(); }
    float cwv = e / red[0];
    __syncthreads();

    float wwn = scal[2] * (scal[1] * alloc_s[t] + (1.f - scal[1]) * cwv);
    ws[OFF_WW + t] = wwn;

    // memory_new + its row norms
    float nn2 = 0.f;
    #pragma unroll
    for (int w = 0; w < 32; ++w) {
        float mn = mrow[w] * (1.f - wwn * er[w]) + wwn * wv[w];
        mrow[w] = mn; nn2 += mn * mn;
        ws[OFF_MEMNEW + t * 32 + w] = mn;
    }
    float inv2 = 1.f / fmaxf(sqrtf(nn2), EPSV);

    if (t < 8) {
        float s = 0.f;
        #pragma unroll
        for (int w = 0; w < 32; ++w) { float v = rk[w * 8 + t]; s += v * v; }
        srk[t] = rs_s[t] / fmaxf(sqrtf(s), EPSV);
    }
    __syncthreads();

    // read content scores + softmax over n per read head
    float sc[8];
    #pragma unroll
    for (int r = 0; r < 8; ++r) {
        float d2 = 0.f;
        #pragma unroll
        for (int w = 0; w < 32; ++w) d2 += mrow[w] * rk[w * 8 + r];
        sc[r] = srk[r] * inv2 * d2;
    }
    #pragma unroll
    for (int r = 0; r < 8; ++r) {
        __syncthreads();
        red[t] = sc[r]; __syncthreads();
        for (int s = 256; s > 0; s >>= 1) { if (t < s) red[t] = fmaxf(red[t], red[t + s]); __syncthreads(); }
        float m2 = red[0]; __syncthreads();
        float e2 = expf(sc[r] - m2);
        red[t] = e2; __syncthreads();
        for (int s = 256; s > 0; s >>= 1) { if (t < s) red[t] += red[t + s]; __syncthreads(); }
        ws[OFF_CR + t * 8 + r] = e2 / red[0];
    }
    if (t < 24) ws[OFF_RM + t] = rm[t];
}

// ---------------- K7: linkage fw/bw ---------------------------------------
__global__ __launch_bounds__(256) void k7_linkage(
    const float* __restrict__ linkage, const float* __restrict__ prec,
    const float* __restrict__ lrw, float* __restrict__ ws)
{
    __shared__ float lrw_s[4096];
    __shared__ float ww_s[512];
    __shared__ float red2[2048];
    const int t = threadIdx.x, blk = blockIdx.x;
    for (int i = t; i < 4096; i += 256) lrw_s[i] = lrw[i];
    for (int i = t; i < 512; i += 256)  ww_s[i] = ws[OFF_WW + i];
    __syncthreads();

    if (blk < 512) {
        // fw[i][r] = sum_j Lm[i][j] * lrw[j][r]
        const int i = blk;
        const float ww_i = ww_s[i];
        float facc[8] = {0,0,0,0,0,0,0,0};
        for (int j = t; j < 512; j += 256) {
            float Lm = (j == i) ? 0.f
                     : (1.f - ww_i - ww_s[j]) * linkage[(size_t)i * 512 + j] + ww_i * prec[j];
            #pragma unroll
            for (int r = 0; r < 8; ++r) facc[r] += Lm * lrw_s[j * 8 + r];
        }
        #pragma unroll
        for (int r = 0; r < 8; ++r) red2[t * 8 + r] = facc[r];
        __syncthreads();
        for (int s = 128; s > 0; s >>= 1) {
            if (t < s) {
                #pragma unroll
                for (int r = 0; r < 8; ++r) red2[t * 8 + r] += red2[(t + s) * 8 + r];
            }
            __syncthreads();
        }
        if (t < 8) ws[OFF_FW + i * 8 + t] = red2[t];
    } else {
        // bw[i][r] = sum_j Lm[j][i] * lrw[j][r]
        const int bb = blk - 512;            // 0..7
        const int ii = t & 63, p = t >> 6;   // 4 j-slices of 128
        const int i = bb * 64 + ii;
        const float ww_i = ww_s[i], prec_i = prec[i];
        float bacc[8] = {0,0,0,0,0,0,0,0};
        for (int j = p * 128; j < p * 128 + 128; ++j) {
            float lj  = linkage[(size_t)j * 512 + i];
            float wwj = ww_s[j];
            float Lm  = (j == i) ? 0.f : (1.f - wwj - ww_i) * lj + wwj * prec_i;
            #pragma unroll
            for (int r = 0; r < 8; ++r) bacc[r] += Lm * lrw_s[j * 8 + r];
        }
        #pragma unroll
        for (int r = 0; r < 8; ++r) red2[t * 8 + r] = bacc[r];
        __syncthreads();
        if (p == 0) {
            #pragma unroll
            for (int r = 0; r < 8; ++r) {
                float s = red2[t * 8 + r] + red2[(t + 64) * 8 + r]
                        + red2[(t + 128) * 8 + r] + red2[(t + 192) * 8 + r];
                ws[OFF_BW + i * 8 + r] = s;
            }
        }
    }
}

// ---------------- K8a: rw + rv --------------------------------------------
__global__ __launch_bounds__(256) void k8a_rv(float* __restrict__ ws)
{
    const int t = threadIdx.x;
    const int w = t >> 3, r = t & 7;
    __shared__ float rm[24];
    if (t < 24) rm[t] = ws[OFF_RM + t];
    __syncthreads();
    const float m0 = rm[r * 3], m1 = rm[r * 3 + 1], m2 = rm[r * 3 + 2];
    float acc = 0.f;
    for (int n = 0; n < 512; ++n) {
        float rwv = ws[OFF_BW + n * 8 + r] * m0
                  + ws[OFF_CR + n * 8 + r] * m1
                  + ws[OFF_FW + n * 8 + r] * m2;
        acc += ws[OFF_MEMNEW + n * 32 + w] * rwv;
    }
    ws[OFF_RV + w * 8 + r] = acc;   // rv flattened as w*R + r
}

// ---------------- K8b: y += rv @ W_r --------------------------------------
__global__ __launch_bounds__(256) void k8b_wr(
    const float* __restrict__ Wr, float* __restrict__ dout,
    const float* __restrict__ ws)
{
    const int blk = blockIdx.x, t = threadIdx.x;
    const int vt = blk % 15, kc = blk / 15;     // 2 k-chunks of 128
    __shared__ float rv_s[128];
    if (t < 128) rv_s[t] = ws[OFF_RV + kc * 128 + t];
    __syncthreads();
    int v = vt * 256 + t;
    if (v < VTDIM) {
        float acc = 0.f;
        const float* Wp = Wr + (size_t)kc * 128 * VTDIM + v;
        #pragma unroll 8
        for (int k = 0; k < 128; ++k) acc += rv_s[k] * Wp[(size_t)k * VTDIM];
        atomicAdd(&dout[v], acc);
    }
}

extern "C" void kernel_launch(void* const* d_in, const int* in_sizes, int n_in,
                              void* d_out, int out_size, void* d_ws, size_t ws_size,
                              hipStream_t stream)
{
    const float* x_in   = (const float*)d_in[0];
    const float* Wi     = (const float*)d_in[1];
    const float* bi     = (const float*)d_in[2];
    const float* Wf     = (const float*)d_in[3];
    const float* bf     = (const float*)d_in[4];
    const float* Wo     = (const float*)d_in[5];
    const float* bo     = (const float*)d_in[6];
    const float* Wss    = (const float*)d_in[7];
    const float* bs     = (const float*)d_in[8];
    const float* Wy     = (const float*)d_in[9];
    const float* We     = (const float*)d_in[10];
    const float* Wr     = (const float*)d_in[11];
    const float* memory = (const float*)d_in[12];
    const float* lrv    = (const float*)d_in[13];
    const float* hprev  = (const float*)d_in[14];
    const float* old_st = (const float*)d_in[15];
    const float* prec   = (const float*)d_in[16];
    const float* linkage= (const float*)d_in[17];
    const float* lrw    = (const float*)d_in[18];
    const float* lu     = (const float*)d_in[19];
    const float* lww    = (const float*)d_in[20];
    float* out = (float*)d_out;
    float* ws  = (float*)d_ws;

    hipMemsetAsync(out, 0, (size_t)VTDIM * sizeof(float), stream);
    hipMemsetAsync(ws + OFF_ERAW, 0, 512 * sizeof(float), stream);

    k1_partial<<<32 * NCHUNK, 256, 0, stream>>>(x_in, lrv, hprev, Wi, Wf, Wo, Wss, ws);
    k2_reduce_compact<<<544, 256, 0, stream>>>(Wi, Wf, Wo, Wss, bi, bf, bo, bs, ws);
    k3_recurrent<<<1, 512, 0, stream>>>(old_st, ws);
    k45_out_E<<<128, 256, 0, stream>>>(Wy, We, out, ws);
    k6_small<<<1, 512, 0, stream>>>(memory, lrw, lu, lww, ws);
    k7_linkage<<<520, 256, 0, stream>>>(linkage, prec, lrw, ws);
    k8a_rv<<<1, 256, 0, stream>>>(ws);
    k8b_wr<<<30, 256, 0, stream>>>(Wr, out, ws);
}

// Round 2
// 318.791 us; speedup vs baseline: 1.0734x; 1.0734x over previous
//
#include <hip/hip_runtime.h>
#include <math.h>

#define XDIM 47764
#define HDIM 128
#define LDIM 8
#define VTDIM 3620
#define WDIM 32
#define RDIM 8
#define NDIM 512
#define RW 256            // W*R
#define DDIM 48276        // X + RW + 2H
#define FIXED 48148       // X + RW + H (rows of si independent of h_prev_layer)
#define ETDIM 395
#define EPSV 1e-8f

#define CHUNK 768
#define NCHUNK 63         // ceil(48148/768)
#define K1_COMPUTE (32 * NCHUNK)   // 2016
#define K1_COPY 512

// ws layout (float offsets)
#define OFF_PARTIAL 0          // 32*63*128 = 258048
#define OFF_WREC    262144     // 32*128*128 = 524288
#define OFF_FLAT    786432     // 1024
#define OFF_ERAW    787456     // 512
#define OFF_WW      787968     // 512
#define OFF_MEMNEW  788480     // 16384
#define OFF_CR      804864     // 4096
#define OFF_RM      808960     // 32
#define OFF_FW      808992     // 4096
#define OFF_BW      813088     // 4096

__device__ inline float sigm(float x) { return 1.f / (1.f + expf(-x)); }
__device__ inline float log_sigmoid(float x) {
    return (x >= 0.f) ? -log1pf(expf(-x)) : (x - log1pf(expf(x)));
}

// ---------------- K1: partial gate pre-activations + weight compaction ------
__global__ __launch_bounds__(256) void k1_partial(
    const float* __restrict__ x_in, const float* __restrict__ lrv,
    const float* __restrict__ hprev,
    const float* __restrict__ Wi, const float* __restrict__ Wf,
    const float* __restrict__ Wo, const float* __restrict__ Ws,
    float* __restrict__ ws)
{
    const int bid = blockIdx.x;
    const int t   = threadIdx.x;

    if (bid >= K1_COMPUTE) {
        // compaction: W*[l][FIXED+j][h] -> wrec[combo][j][h], 1 float4/thread
        int idx4  = (bid - K1_COMPUTE) * 256 + t;
        int flat  = idx4 << 2;
        int combo = flat >> 14;
        int rem   = flat & 16383;
        int j = rem >> 7, h = rem & 127;
        int g = combo >> 3, l = combo & 7;
        const float* Wg = (g == 0) ? Wi : (g == 1) ? Wf : (g == 2) ? Wo : Ws;
        float4 v = *reinterpret_cast<const float4*>(
            Wg + ((size_t)l * DDIM + FIXED + j) * HDIM + h);
        *reinterpret_cast<float4*>(ws + OFF_WREC + flat) = v;
        return;
    }

    const int combo = bid / NCHUNK;
    const int chunk = bid % NCHUNK;
    const int g = combo >> 3, l = combo & 7;
    const float* __restrict__ Wg = (g == 0) ? Wi : (g == 1) ? Wf : (g == 2) ? Wo : Ws;
    const int d0 = chunk * CHUNK;

    __shared__ float s_lds[CHUNK];
    for (int i = t; i < CHUNK; i += 256) {
        int d = d0 + i;
        float v = 0.f;
        if (d < XDIM)            v = x_in[d];
        else if (d < XDIM + RW)  v = lrv[d - XDIM];
        else if (d < FIXED)      v = hprev[l * HDIM + (d - XDIM - RW)];
        s_lds[i] = v;
    }
    __syncthreads();

    const int c4 = t & 15;          // float4 column (0..15) -> cols c4 and c4+16
    const int p  = t >> 4;          // row slice 0..15, each 48 contiguous rows
    const int r0 = p * 48;
    const float* wp = Wg + ((size_t)l * DDIM + d0 + r0) * HDIM + (c4 << 2);

    float4 a = make_float4(0.f, 0.f, 0.f, 0.f);
    float4 b = make_float4(0.f, 0.f, 0.f, 0.f);

    if (chunk != NCHUNK - 1) {
        #pragma unroll 4
        for (int i = 0; i < 48; ++i) {
            float s = s_lds[r0 + i];
            const float4 w0 = *reinterpret_cast<const float4*>(wp);
            const float4 w1 = *reinterpret_cast<const float4*>(wp + 64);
            wp += HDIM;
            a.x += s * w0.x; a.y += s * w0.y; a.z += s * w0.z; a.w += s * w0.w;
            b.x += s * w1.x; b.y += s * w1.y; b.z += s * w1.z; b.w += s * w1.w;
        }
    } else {
        for (int i = 0; i < 48; ++i) {
            if (d0 + r0 + i >= FIXED) break;
            float s = s_lds[r0 + i];
            const float4 w0 = *reinterpret_cast<const float4*>(wp);
            const float4 w1 = *reinterpret_cast<const float4*>(wp + 64);
            wp += HDIM;
            a.x += s * w0.x; a.y += s * w0.y; a.z += s * w0.z; a.w += s * w0.w;
            b.x += s * w1.x; b.y += s * w1.y; b.z += s * w1.z; b.w += s * w1.w;
        }
    }

    __shared__ float4 red[16][32];
    red[p][c4]      = a;
    red[p][c4 + 16] = b;
    __syncthreads();
    if (t < 32) {
        float4 s = red[0][t];
        #pragma unroll
        for (int q = 1; q < 16; ++q) {
            float4 v = red[q][t];
            s.x += v.x; s.y += v.y; s.z += v.z; s.w += v.w;
        }
        *reinterpret_cast<float4*>(ws + OFF_PARTIAL +
            ((size_t)(combo * NCHUNK + chunk)) * HDIM + (t << 2)) = s;
    }
}

// -------- K3: partial-reduce + bias, then sequential layer chain (1 block) --
__global__ __launch_bounds__(1024) void k3_recurrent(
    const float* __restrict__ bi, const float* __restrict__ bf,
    const float* __restrict__ bo, const float* __restrict__ bs,
    const float* __restrict__ old_states, float* __restrict__ ws,
    float* __restrict__ out)
{
    const int t = threadIdx.x;          // 0..1023
    const int g = t >> 8;               // gate 0..3
    const int q = (t >> 7) & 1;         // half of j-dim
    const int h = t & 127;

    __shared__ float fixed_s[32][128];  // 16 KB
    __shared__ float hp[128];
    __shared__ float gl[4][2][128];

    // zero d_out (for k45 atomics) and E_raw
    for (int i = t; i < VTDIM; i += 1024) out[i] = 0.f;
    if (t < 512) ws[OFF_ERAW + t] = 0.f;

    // reduce chunk partials + bias
    const float* bg = (g == 0) ? bi : (g == 1) ? bf : (g == 2) ? bo : bs;
    for (int l = q; l < LDIM; l += 2) {
        int combo = g * 8 + l;
        float acc = bg[l * HDIM + h];
        const float* P = ws + OFF_PARTIAL + (size_t)combo * NCHUNK * HDIM + h;
        for (int c = 0; c < NCHUNK; ++c) acc += P[c * HDIM];
        fixed_s[combo][h] = acc;
    }
    if (t < 128) hp[t] = 0.f;
    __syncthreads();

    for (int l = 0; l < LDIM; ++l) {
        int combo = g * 8 + l;
        float acc = (q == 0) ? fixed_s[combo][h] : 0.f;
        const float* wr = ws + OFF_WREC + (size_t)combo * 16384 + (q << 6) * 128 + h;
        #pragma unroll 8
        for (int j = 0; j < 64; ++j) acc += hp[(q << 6) + j] * wr[j * 128];
        gl[g][q][h] = acc;
        __syncthreads();
        if (t < 128) {
            float ig = sigm(gl[0][0][t] + gl[0][1][t]);
            float fg = sigm(gl[1][0][t] + gl[1][1][t]);
            float og = sigm(gl[2][0][t] + gl[2][1][t]);
            float ss = tanhf(gl[3][0][t] + gl[3][1][t]);
            float st = fg * old_states[l * HDIM + t] + ig * ss;
            float hn = og * tanhf(st);
            hp[t] = hn;
            ws[OFF_FLAT + l * HDIM + t] = hn;
        }
        __syncthreads();
    }
}

// ---------------- K45: flat@W_y -> d_out, flat@W_E -> E_raw ----------------
__global__ __launch_bounds__(256) void k45_out_E(
    const float* __restrict__ Wy, const float* __restrict__ We,
    float* __restrict__ dout, float* __restrict__ ws)
{
    const int blk = blockIdx.x, t = threadIdx.x;
    __shared__ float fl[128];
    if (blk < 120) {
        int vt = blk % 15, kc = blk / 15;
        if (t < 128) fl[t] = ws[OFF_FLAT + kc * 128 + t];
        __syncthreads();
        int v = vt * 256 + t;
        if (v < VTDIM) {
            float acc = 0.f;
            const float* Wp = Wy + (size_t)kc * 128 * VTDIM + v;
            #pragma unroll 8
            for (int k = 0; k < 128; ++k) acc += fl[k] * Wp[(size_t)k * VTDIM];
            atomicAdd(&dout[v], acc);
        }
    } else {
        int kc = blk - 120;
        if (t < 128) fl[t] = ws[OFF_FLAT + kc * 128 + t];
        __syncthreads();
        if (t < ETDIM) {
            float acc = 0.f;
            const float* Wp = We + (size_t)kc * 128 * ETDIM + t;
            #pragma unroll 8
            for (int k = 0; k < 128; ++k) acc += fl[k] * Wp[k * ETDIM];
            atomicAdd(&ws[OFF_ERAW + t], acc);
        }
    }
}

// ------ K6: E unpack + usage/alloc(rank-product) + write/memory/cr ---------
__global__ __launch_bounds__(512) void k6_small(
    const float* __restrict__ memory, const float* __restrict__ lrw,
    const float* __restrict__ lu, const float* __restrict__ lww,
    float* __restrict__ ws)
{
    const int t = threadIdx.x;
    const int lane = t & 63, wid = t >> 6;
    __shared__ float Es[400];
    __shared__ float rk[256], wk[32], er[32], wv[32], fgs[8], rs_s[8], rm[24], scal[3];
    __shared__ float u_s[512];
    __shared__ float wred[8];
    __shared__ float wred8[8][8];
    __shared__ float srk[8];

    if (t < ETDIM) Es[t] = ws[OFF_ERAW + t];
    __syncthreads();

    if (t < 256)                 rk[t] = Es[t];
    if (t >= 256 && t < 264)     rs_s[t - 256] = 1.f - log_sigmoid(Es[t]);
    if (t >= 264 && t < 296)     wk[t - 264] = Es[t];
    if (t == 296)                scal[0] = 1.f - log_sigmoid(Es[296]);   // write_strength
    if (t >= 297 && t < 329)     er[t - 297] = sigm(Es[t]);
    if (t >= 329 && t < 361)     wv[t - 329] = Es[t];
    if (t >= 361 && t < 369)     fgs[t - 361] = sigm(Es[t]);
    if (t == 369)                scal[1] = sigm(Es[369]);                // alloc_gate
    if (t == 370)                scal[2] = sigm(Es[370]);                // write_gate
    if (t >= 384 && t < 392) {                                          // read_modes
        int r = t - 384;
        float a = Es[371 + 3*r], b = Es[372 + 3*r], c = Es[373 + 3*r];
        float mx = fmaxf(a, fmaxf(b, c));
        float ea = expf(a - mx), eb = expf(b - mx), ec = expf(c - mx);
        float s = ea + eb + ec;
        rm[3*r] = ea / s; rm[3*r + 1] = eb / s; rm[3*r + 2] = ec / s;
    }
    __syncthreads();

    // usage
    float psi = 1.f;
    #pragma unroll
    for (int r = 0; r < 8; ++r) psi *= 1.f - fgs[r] * lrw[t * 8 + r];
    float ua = lu[t], ub = lww[t];
    float u_t = (ua + ub - ua * ub) * psi;
    u_s[t] = u_t;
    __syncthreads();

    // alloc[t] = (1-u_t) * prod over (u_j,j) lexicographically before (u_t,t)
    float prod = 1.f;
    for (int j = 0; j < 512; ++j) {
        float uj = u_s[j];
        bool before = (uj < u_t) || (uj == u_t && j < t);
        prod *= before ? uj : 1.f;
    }
    float alloc_t = (1.f - u_t) * prod;

    // write-key norm (every thread, broadcast reads)
    float s2 = 0.f;
    #pragma unroll
    for (int w = 0; w < 32; ++w) s2 += wk[w] * wk[w];
    float wkinv = 1.f / fmaxf(sqrtf(s2), EPSV);

    // content write score
    float mrow[32];
    float dotv = 0.f, nn = 0.f;
    #pragma unroll
    for (int w = 0; w < 32; ++w) {
        float m = memory[t * 32 + w];
        mrow[w] = m; dotv += m * wk[w]; nn += m * m;
    }
    float score = scal[0] * wkinv * dotv / fmaxf(sqrtf(nn), EPSV);
    float v = score;
    #pragma unroll
    for (int o = 32; o > 0; o >>= 1) v = fmaxf(v, __shfl_xor(v, o));
    if (lane == 0) wred[wid] = v;
    __syncthreads();
    float mx = wred[0];
    #pragma unroll
    for (int qq = 1; qq < 8; ++qq) mx = fmaxf(mx, wred[qq]);
    __syncthreads();
    float e = expf(score - mx);
    v = e;
    #pragma unroll
    for (int o = 32; o > 0; o >>= 1) v += __shfl_xor(v, o);
    if (lane == 0) wred[wid] = v;
    __syncthreads();
    float ssum = 0.f;
    #pragma unroll
    for (int qq = 0; qq < 8; ++qq) ssum += wred[qq];
    float cwv = e / ssum;

    float wwn = scal[2] * (scal[1] * alloc_t + (1.f - scal[1]) * cwv);
    ws[OFF_WW + t] = wwn;

    // memory_new + row norm
    float nn2 = 0.f;
    #pragma unroll
    for (int w = 0; w < 32; ++w) {
        float mn = mrow[w] * (1.f - wwn * er[w]) + wwn * wv[w];
        mrow[w] = mn; nn2 += mn * mn;
        ws[OFF_MEMNEW + t * 32 + w] = mn;
    }
    float inv2 = 1.f / fmaxf(sqrtf(nn2), EPSV);

    if (t < 8) {
        float s3 = 0.f;
        #pragma unroll
        for (int w = 0; w < 32; ++w) { float x = rk[w * 8 + t]; s3 += x * x; }
        srk[t] = rs_s[t] / fmaxf(sqrtf(s3), EPSV);
    }
    __syncthreads();

    // read content scores + softmax over n per head (shfl reductions)
    float sc[8];
    #pragma unroll
    for (int r = 0; r < 8; ++r) {
        float d2 = 0.f;
        #pragma unroll
        for (int w = 0; w < 32; ++w) d2 += mrow[w] * rk[w * 8 + r];
        sc[r] = srk[r] * inv2 * d2;
    }
    #pragma unroll
    for (int r = 0; r < 8; ++r) {
        float x = sc[r];
        #pragma unroll
        for (int o = 32; o > 0; o >>= 1) x = fmaxf(x, __shfl_xor(x, o));
        if (lane == 0) wred8[wid][r] = x;
    }
    __syncthreads();
    float mxr[8];
    #pragma unroll
    for (int r = 0; r < 8; ++r) {
        float m = wred8[0][r];
        #pragma unroll
        for (int qq = 1; qq < 8; ++qq) m = fmaxf(m, wred8[qq][r]);
        mxr[r] = m;
    }
    __syncthreads();
    float ex[8];
    #pragma unroll
    for (int r = 0; r < 8; ++r) {
        ex[r] = expf(sc[r] - mxr[r]);
        float x = ex[r];
        #pragma unroll
        for (int o = 32; o > 0; o >>= 1) x += __shfl_xor(x, o);
        if (lane == 0) wred8[wid][r] = x;
    }
    __syncthreads();
    #pragma unroll
    for (int r = 0; r < 8; ++r) {
        float sm = 0.f;
        #pragma unroll
        for (int qq = 0; qq < 8; ++qq) sm += wred8[qq][r];
        ws[OFF_CR + t * 8 + r] = ex[r] / sm;
    }
    if (t < 24) ws[OFF_RM + t] = rm[t];
}

// ---------------- K7: linkage fw/bw ---------------------------------------
__global__ __launch_bounds__(256) void k7_linkage(
    const float* __restrict__ linkage, const float* __restrict__ prec,
    const float* __restrict__ lrw, float* __restrict__ ws)
{
    __shared__ float lrw_s[4096];
    __shared__ float ww_s[512];
    __shared__ float red2[2048];
    const int t = threadIdx.x, blk = blockIdx.x;
    for (int i = t; i < 4096; i += 256) lrw_s[i] = lrw[i];
    for (int i = t; i < 512; i += 256)  ww_s[i] = ws[OFF_WW + i];
    __syncthreads();

    if (blk < 512) {
        const int i = blk;
        const float ww_i = ww_s[i];
        float facc[8] = {0,0,0,0,0,0,0,0};
        for (int j = t; j < 512; j += 256) {
            float Lm = (j == i) ? 0.f
                     : (1.f - ww_i - ww_s[j]) * linkage[(size_t)i * 512 + j] + ww_i * prec[j];
            #pragma unroll
            for (int r = 0; r < 8; ++r) facc[r] += Lm * lrw_s[j * 8 + r];
        }
        #pragma unroll
        for (int r = 0; r < 8; ++r) red2[t * 8 + r] = facc[r];
        __syncthreads();
        for (int s = 128; s > 0; s >>= 1) {
            if (t < s) {
                #pragma unroll
                for (int r = 0; r < 8; ++r) red2[t * 8 + r] += red2[(t + s) * 8 + r];
            }
            __syncthreads();
        }
        if (t < 8) ws[OFF_FW + i * 8 + t] = red2[t];
    } else {
        const int bb = blk - 512;
        const int ii = t & 63, p = t >> 6;
        const int i = bb * 64 + ii;
        const float ww_i = ww_s[i], prec_i = prec[i];
        float bacc[8] = {0,0,0,0,0,0,0,0};
        for (int j = p * 128; j < p * 128 + 128; ++j) {
            float lj  = linkage[(size_t)j * 512 + i];
            float wwj = ww_s[j];
            float Lm  = (j == i) ? 0.f : (1.f - wwj - ww_i) * lj + wwj * prec_i;
            #pragma unroll
            for (int r = 0; r < 8; ++r) bacc[r] += Lm * lrw_s[j * 8 + r];
        }
        #pragma unroll
        for (int r = 0; r < 8; ++r) red2[t * 8 + r] = bacc[r];
        __syncthreads();
        if (p == 0) {
            #pragma unroll
            for (int r = 0; r < 8; ++r) {
                float s = red2[t * 8 + r] + red2[(t + 64) * 8 + r]
                        + red2[(t + 128) * 8 + r] + red2[(t + 192) * 8 + r];
                ws[OFF_BW + i * 8 + r] = s;
            }
        }
    }
}

// ------- K8: rw -> rv (in-LDS, per-block) -> y += rv @ W_r -----------------
__global__ __launch_bounds__(256) void k8_read_out(
    const float* __restrict__ Wr, float* __restrict__ dout,
    const float* __restrict__ ws)
{
    __shared__ float mn_s[NDIM * 32];     // 64 KB
    __shared__ float rw_s[NDIM * 8];      // 16 KB
    __shared__ float rred[8][32][8];      // 8 KB
    __shared__ float rv_s[256];
    __shared__ float rm_s[24];
    const int t = threadIdx.x;

    for (int i = t; i < NDIM * 8; i += 256)   // 16384 floats as float4
        *reinterpret_cast<float4*>(mn_s + (i << 2)) =
            *reinterpret_cast<const float4*>(ws + OFF_MEMNEW + (i << 2));
    if (t < 24) rm_s[t] = ws[OFF_RM + t];
    __syncthreads();

    for (int idx = t; idx < 4096; idx += 256) {
        int r = idx & 7;
        rw_s[idx] = ws[OFF_BW + idx] * rm_s[r * 3]
                  + ws[OFF_CR + idx] * rm_s[r * 3 + 1]
                  + ws[OFF_FW + idx] * rm_s[r * 3 + 2];
    }
    __syncthreads();

    const int g = t >> 5, w = t & 31;
    float acc[8] = {0,0,0,0,0,0,0,0};
    for (int n = g * 64; n < g * 64 + 64; ++n) {
        float m = mn_s[n * 32 + w];
        #pragma unroll
        for (int r = 0; r < 8; ++r) acc[r] += m * rw_s[n * 8 + r];
    }
    #pragma unroll
    for (int r = 0; r < 8; ++r) rred[g][w][r] = acc[r];
    __syncthreads();
    {
        int w2 = t >> 3, r2 = t & 7;
        float s = 0.f;
        #pragma unroll
        for (int qq = 0; qq < 8; ++qq) s += rred[qq][w2][r2];
        rv_s[w2 * 8 + r2] = s;
    }
    __syncthreads();

    int v = blockIdx.x * 256 + t;
    if (v < VTDIM) {
        float acc2 = 0.f;
        const float* Wp = Wr + v;
        #pragma unroll 8
        for (int k = 0; k < 256; ++k) acc2 += rv_s[k] * Wp[(size_t)k * VTDIM];
        dout[v] += acc2;
    }
}

extern "C" void kernel_launch(void* const* d_in, const int* in_sizes, int n_in,
                              void* d_out, int out_size, void* d_ws, size_t ws_size,
                              hipStream_t stream)
{
    const float* x_in   = (const float*)d_in[0];
    const float* Wi     = (const float*)d_in[1];
    const float* bi     = (const float*)d_in[2];
    const float* Wf     = (const float*)d_in[3];
    const float* bf     = (const float*)d_in[4];
    const float* Wo     = (const float*)d_in[5];
    const float* bo     = (const float*)d_in[6];
    const float* Wss    = (const float*)d_in[7];
    const float* bs     = (const float*)d_in[8];
    const float* Wy     = (const float*)d_in[9];
    const float* We     = (const float*)d_in[10];
    const float* Wr     = (const float*)d_in[11];
    const float* memory = (const float*)d_in[12];
    const float* lrv    = (const float*)d_in[13];
    const float* hprev  = (const float*)d_in[14];
    const float* old_st = (const float*)d_in[15];
    const float* prec   = (const float*)d_in[16];
    const float* linkage= (const float*)d_in[17];
    const float* lrw    = (const float*)d_in[18];
    const float* lu     = (const float*)d_in[19];
    const float* lww    = (const float*)d_in[20];
    float* out = (float*)d_out;
    float* ws  = (float*)d_ws;

    k1_partial<<<K1_COMPUTE + K1_COPY, 256, 0, stream>>>(x_in, lrv, hprev, Wi, Wf, Wo, Wss, ws);
    k3_recurrent<<<1, 1024, 0, stream>>>(bi, bf, bo, bs, old_st, ws, out);
    k45_out_E<<<128, 256, 0, stream>>>(Wy, We, out, ws);
    k6_small<<<1, 512, 0, stream>>>(memory, lrw, lu, lww, ws);
    k7_linkage<<<520, 256, 0, stream>>>(linkage, prec, lrw, ws);
    k8_read_out<<<15, 256, 0, stream>>>(Wr, out, ws);
}